// Round 8
// baseline (157.756 us; speedup 1.0000x reference)
//
#include <hip/hip_runtime.h>
#include <hip/hip_bf16.h>

// cross_set_score, fused one-pass. x[64,64,64,256] f32 (M=64, F=256).
// out[p,q]=out[q,p]= sum_h W2[h]*0.125*relu-sum(hA·hB^T) / (nItem[p]*nItem[q]);
// hA=x[p,q]@W1, hB=x[q,p]@W1 (bf16 MFMA in-block).
// 2080 blocks (one per unordered pair) x 512 thr (8 waves).
// VGPR discipline (lesson of r4-r7): no staging regs live across compute;
// proj acc = [2][4] (32 VGPR) via two sequential 32-row units. The in-place
// h-overwrite stays legal: unit 0 reads only x rows 0-31, so after one
// barrier h rows 0-31 overwrite x rows 0-31 while unit 1 reads rows 32-63.
// LDS 67.6 KiB -> 2 blocks/CU = 16 waves/CU (4/SIMD, 128-VGPR cap).

#define NSET 64
#define MITEM 64
#define FFEAT 256

typedef float f32x4 __attribute__((ext_vector_type(4)));
typedef short bf16x8 __attribute__((ext_vector_type(8)));
typedef unsigned short u16;
typedef u16 u16x4 __attribute__((ext_vector_type(4)));

__device__ __forceinline__ u16 f2bf(float f) {
    __bf16 b = (__bf16)f;
    return __builtin_bit_cast(u16, b);
}
__device__ __forceinline__ f32x4 mfma16(bf16x8 a, bf16x8 b, f32x4 c) {
    return __builtin_amdgcn_mfma_f32_16x16x32_bf16(a, b, c, 0, 0, 0);
}

// ---- prep: W1 [k=256][c=256] f32 -> W1T bf16 [c][k] (B-frags contiguous in k)
__global__ void prep_w1t_kernel(const float* __restrict__ w1, u16* __restrict__ w1t) {
    int c = blockIdx.x, k = threadIdx.x;
    w1t[c * 256 + k] = f2bf(w1[k * 256 + c]);
}

__global__ __launch_bounds__(512, 4) void fused_kernel(const float* __restrict__ x,
                                                       const u16* __restrict__ w1t,
                                                       const float* __restrict__ nItem,
                                                       const float* __restrict__ W2,
                                                       float* __restrict__ out) {
    // [64 rows][264 cols] bf16, 528 B stride (16B-mult; 2-way bank alias free).
    // Holds x-slice (bf16) during projection, then overwritten with h.
    __shared__ u16 BUFA[MITEM][264];   // 33.8 KiB
    __shared__ u16 BUFB[MITEM][264];   // 33.8 KiB
    __shared__ float red[8];

    int p = 0, rem = blockIdx.x;
    while (rem >= NSET - p) { rem -= NSET - p; ++p; }
    const int q = p + rem;

    const float* xA = x + (size_t)(p * NSET + q) * (MITEM * FFEAT);
    const float* xB = x + (size_t)(q * NSET + p) * (MITEM * FFEAT);

    const int tid  = threadIdx.x;
    const int lane = tid & 63;
    const int wave = tid >> 6;          // 0..7
    const int ar   = lane & 15;
    const int kg   = lane >> 4;
    const int k0   = kg * 8;

    // ---------------- phase 0: stage x -> LDS bf16 (phase-local regs only) ----
    // 16384 f32/slice; 512 thr x float4: per instr one wave covers 1 KiB.
    {
        float4 ra[8], rb[8];
#pragma unroll
        for (int u = 0; u < 8; ++u) {
            const int f = u * 2048 + tid * 4;
            ra[u] = *(const float4*)(xA + f);
            rb[u] = *(const float4*)(xB + f);
        }
#pragma unroll
        for (int u = 0; u < 8; ++u) {
            const int f = u * 2048 + tid * 4;
            const int r = f >> 8, c = f & 255;
            u16x4 pa = { f2bf(ra[u].x), f2bf(ra[u].y), f2bf(ra[u].z), f2bf(ra[u].w) };
            u16x4 pb = { f2bf(rb[u].x), f2bf(rb[u].y), f2bf(rb[u].z), f2bf(rb[u].w) };
            *(u16x4*)&BUFA[r][c] = pa;
            *(u16x4*)&BUFB[r][c] = pb;
        }
    }
    __syncthreads();

    // ---------------- phase 1: projection, two 32-row units per wave ----------
    // wave = (sel = wave>>2 slice, g = wave&3 64-col group); acc[2][4] = 32 VGPR.
    const int g   = wave & 3;
    const int sel = wave >> 2;
    u16 (*BUF)[264] = sel ? BUFB : BUFA;
    const u16* wb = w1t + (size_t)(g * 64 + ar) * 256 + k0;   // + u*16*256 + kc*32

#pragma unroll
    for (int un = 0; un < 2; ++un) {
        f32x4 acc[2][4] = {};
        bf16x8 bcur[4];
#pragma unroll
        for (int u = 0; u < 4; ++u)
            bcur[u] = *(const bf16x8*)(wb + (size_t)(u * 16) * 256);
#pragma unroll
        for (int kc = 0; kc < 8; ++kc) {
            bf16x8 a0 = *(const bf16x8*)&BUF[un * 32 +  0 + ar][kc * 32 + k0];
            bf16x8 a1 = *(const bf16x8*)&BUF[un * 32 + 16 + ar][kc * 32 + k0];
            bf16x8 bnxt[4];
            if (kc < 7) {   // 1-deep prefetch breaks the L1/L2 latency chain
#pragma unroll
                for (int u = 0; u < 4; ++u)
                    bnxt[u] = *(const bf16x8*)(wb + (size_t)(u * 16) * 256
                                                  + (kc + 1) * 32);
            }
#pragma unroll
            for (int u = 0; u < 4; ++u) {
                acc[0][u] = mfma16(a0, bcur[u], acc[0][u]);
                acc[1][u] = mfma16(a1, bcur[u], acc[1][u]);
            }
#pragma unroll
            for (int u = 0; u < 4; ++u) bcur[u] = bnxt[u];
        }
        __syncthreads();   // ALL waves done reading x rows [un*32, un*32+32)

        // write h rows of this unit over the same x rows (disjoint from unit 1's
        // reads when un==0). C/D layout: col = lane&15, row = (lane>>4)*4+j [m89]
#pragma unroll
        for (int rt = 0; rt < 2; ++rt)
#pragma unroll
            for (int u = 0; u < 4; ++u) {
                const int cc = g * 64 + u * 16 + ar;
#pragma unroll
                for (int j = 0; j < 4; ++j)
                    BUF[un * 32 + rt * 16 + kg * 4 + j][cc] = f2bf(acc[rt][u][j]);
            }
    }
    __syncthreads();   // h fully visible

    // ---------------- phase 2: score, wave = (head hd, row-half rh) -----------
    float sum = 0.f;
    {
        const int hd = wave & 3, rh = wave >> 2;
        const int hc = hd * 64;
        bf16x8 aS[2][2];
#pragma unroll
        for (int rt = 0; rt < 2; ++rt)
#pragma unroll
            for (int kk = 0; kk < 2; ++kk)
                aS[rt][kk] = *(const bf16x8*)
                    &BUFA[rh * 32 + rt * 16 + ar][hc + kk * 32 + k0];
#pragma unroll
        for (int bu = 0; bu < 4; ++bu) {
            bf16x8 b0 = *(const bf16x8*)&BUFB[bu * 16 + ar][hc + k0];
            bf16x8 b1 = *(const bf16x8*)&BUFB[bu * 16 + ar][hc + 32 + k0];
#pragma unroll
            for (int rt = 0; rt < 2; ++rt) {
                f32x4 c = {};
                c = mfma16(aS[rt][0], b0, c);
                c = mfma16(aS[rt][1], b1, c);   // full k=64 BEFORE relu
                sum += fmaxf(c[0], 0.f) + fmaxf(c[1], 0.f) +
                       fmaxf(c[2], 0.f) + fmaxf(c[3], 0.f);
            }
        }
    }

    // ---------------- phase 3: reduce + output --------------------------------
#pragma unroll
    for (int off = 32; off; off >>= 1) sum += __shfl_xor(sum, off);
    if (lane == 0) red[wave] = sum;
    __syncthreads();
    if (tid == 0) {
        const float nP = nItem[p], nQ = nItem[q];
        float v = 0.f;
#pragma unroll
        for (int h = 0; h < 4; ++h)
            v += ((((red[h] + red[h + 4]) * 0.125f) / nQ) / nP) * W2[h];
        out[p * NSET + q] = v;
        out[q * NSET + p] = v;
    }
}

extern "C" void kernel_launch(void* const* d_in, const int* in_sizes, int n_in,
                              void* d_out, int out_size, void* d_ws, size_t ws_size,
                              hipStream_t stream) {
    const float* x     = (const float*)d_in[0];
    const float* nItem = (const float*)d_in[1];
    const float* W1    = (const float*)d_in[2];
    const float* W2    = (const float*)d_in[3];
    float* out = (float*)d_out;

    u16* w1t = (u16*)d_ws;                 // 128 KiB
    if (ws_size < 131072) return;

    hipLaunchKernelGGL(prep_w1t_kernel, dim3(256), dim3(256), 0, stream, W1, w1t);
    hipLaunchKernelGGL(fused_kernel, dim3(2080), dim3(512), 0, stream,
                       x, w1t, nItem, W2, out);
}

// Round 9
// 147.305 us; speedup vs baseline: 1.0709x; 1.0709x over previous
//
#include <hip/hip_runtime.h>
#include <hip/hip_bf16.h>

// cross_set_score, fused, async-pipelined. x[64,64,64,256] f32 (M=64, F=256).
// out[p,q]=out[q,p]= sum_h W2[h]*0.125*relu-sum(hA·hB^T) / (nItem[p]*nItem[q]);
// hA=x[p,q]@W1, hB=x[q,p]@W1 (bf16 MFMA in-block).
//
// Structure (lesson r3-r8: HBM duty cycle is the limit; register prefetch spills):
// 256 persistent blocks (1/CU) x 512 thr (8 waves). x streamed via
// global_load_lds (zero VGPR) in [64x32]-f32 chunks, 3-deep ring, counted
// s_waitcnt vmcnt(4) + raw s_barrier (T3/T4) so loads stay in flight across
// barriers; the chunk stream crosses pair boundaries (score overlaps next
// pair's loads). A-frags: f32-from-LDS + in-reg cvt; XOR-slot swizzle applied
// on the GLOBAL source (LDS dest linear, rule #21) and on the LDS read.

#define NSET 64
#define MITEM 64
#define FFEAT 256
#define NPAIR 2080
#define NBLK 256

typedef float f32x4 __attribute__((ext_vector_type(4)));
typedef short bf16x8 __attribute__((ext_vector_type(8)));
typedef unsigned short u16;

typedef const __attribute__((address_space(1))) void* gas_ptr;
typedef __attribute__((address_space(3))) void* las_ptr;

__device__ __forceinline__ u16 f2bf(float f) {
    __bf16 b = (__bf16)f;
    return __builtin_bit_cast(u16, b);
}
__device__ __forceinline__ bf16x8 pack8(const float4& a, const float4& b) {
    bf16x8 r;
    r[0] = (short)f2bf(a.x); r[1] = (short)f2bf(a.y);
    r[2] = (short)f2bf(a.z); r[3] = (short)f2bf(a.w);
    r[4] = (short)f2bf(b.x); r[5] = (short)f2bf(b.y);
    r[6] = (short)f2bf(b.z); r[7] = (short)f2bf(b.w);
    return r;
}
__device__ __forceinline__ f32x4 mfma16(bf16x8 a, bf16x8 b, f32x4 c) {
    return __builtin_amdgcn_mfma_f32_16x16x32_bf16(a, b, c, 0, 0, 0);
}
__device__ __forceinline__ void gll16(const float* g, float* l) {
    __builtin_amdgcn_global_load_lds((gas_ptr)g, (las_ptr)l, 16, 0, 0);
}
__device__ __forceinline__ void decode_pair(int idx, int& p, int& q) {
    p = 0;
    while (idx >= NSET - p) { idx -= NSET - p; ++p; }
    q = p + idx;
}

// ---- prep: W1 [k=256][c=256] f32 -> W1T bf16 [c][k] (B-frags contiguous in k)
__global__ void prep_w1t_kernel(const float* __restrict__ w1, u16* __restrict__ w1t) {
    int c = blockIdx.x, k = threadIdx.x;
    w1t[c * 256 + k] = f2bf(w1[k * 256 + c]);
}

// issue one chunk (both slices' [64][32] f32) for this wave: 2 x 1KiB DMA calls.
// Global source pre-swizzled: 16B-slot sl fetches global slot (sl ^ row&7) so
// the linear LDS holds the XOR-swizzled layout (bank-spread on ds_read).
__device__ __forceinline__ void issue_chunk(float (*XCH)[2][64][32], int buf,
                                            const float* xA, const float* xB,
                                            int kc, int wave, int lane) {
    const int s  = wave >> 2;
    const float* xs = s ? xB : xA;
    const int rr = lane >> 3, sl = lane & 7;
    const int coff = kc * 32 + ((sl ^ rr) << 2);
#pragma unroll
    for (int c = 0; c < 2; ++c) {
        const int rb = (wave * 2 + c) & 7;
        gll16(xs + (size_t)(rb * 8 + rr) * FFEAT + coff, &XCH[buf][s][rb * 8][0]);
    }
}

__global__ __launch_bounds__(512, 2) void fused_kernel(const float* __restrict__ x,
                                                       const u16* __restrict__ w1t,
                                                       const float* __restrict__ nItem,
                                                       const float* __restrict__ W2,
                                                       float* __restrict__ out) {
    __shared__ float XCH[3][2][MITEM][32];   // 48 KiB: 3-deep chunk ring, LINEAR
    __shared__ u16 HA[MITEM][264];           // 33.8 KiB (528 B stride)
    __shared__ u16 HB[MITEM][264];           // 33.8 KiB
    __shared__ float red[8];

    const int tid  = threadIdx.x;
    const int lane = tid & 63;
    const int wave = tid >> 6;          // 0..7
    const int ar   = lane & 15;
    const int kg   = lane >> 4;         // 0..3
    const int k0   = kg * 8;
    const int g    = wave & 3;          // proj 64-col group / score head
    const int sel  = wave >> 2;         // proj slice (matches issue slice)

    const int bid = blockIdx.x;
    const int np  = (bid < 32) ? 9 : 8;           // 2080 = 8*256 + 32

    int idx = bid;
    int p, q; decode_pair(idx, p, q);
    const float* xAc = x + (size_t)(p * NSET + q) * (MITEM * FFEAT);
    const float* xBc = x + (size_t)(q * NSET + p) * (MITEM * FFEAT);
    int nidx = idx + NBLK;
    int pn, qn; decode_pair(nidx < NPAIR ? nidx : idx, pn, qn);
    const float* xAn = x + (size_t)(pn * NSET + qn) * (MITEM * FFEAT);
    const float* xBn = x + (size_t)(qn * NSET + pn) * (MITEM * FFEAT);

    // prologue: 3 chunks in flight (6 calls/wave)
    issue_chunk(XCH, 0, xAc, xBc, 0, wave, lane);
    issue_chunk(XCH, 1, xAc, xBc, 1, wave, lane);
    issue_chunk(XCH, 2, xAc, xBc, 2, wave, lane);

    int bc = 0;   // ring slot holding current chunk

    for (int k = 0; k < np; ++k) {
        f32x4 acc[4][4] = {};
#pragma unroll
        for (int kc = 0; kc < 8; ++kc) {
            // wait current chunk landed (2 calls x 2 deeper chunks still flying)
            asm volatile("s_waitcnt vmcnt(4)" ::: "memory");
            __builtin_amdgcn_s_barrier();
            __builtin_amdgcn_sched_barrier(0);

            const float* XB = &XCH[bc][sel][0][0];
#pragma unroll
            for (int rt = 0; rt < 4; ++rt) {
                const int rw = rt * 16 + ar;
                const float* rbase = XB + rw * 32;
                const int key = rw & 7;
                float4 f0 = *(const float4*)(rbase + (((2 * kg + 0) ^ key) << 2));
                float4 f1 = *(const float4*)(rbase + (((2 * kg + 1) ^ key) << 2));
                bf16x8 a = pack8(f0, f1);
#pragma unroll
                for (int u = 0; u < 4; ++u) {
                    bf16x8 bu = *(const bf16x8*)(w1t
                        + (size_t)(g * 64 + u * 16 + ar) * 256 + kc * 32 + k0);
                    acc[rt][u] = mfma16(a, bu, acc[rt][u]);
                }
            }
            // all waves done reading ring slot bc
            __builtin_amdgcn_s_barrier();
            __builtin_amdgcn_sched_barrier(0);

            // refill freed slot with chunk (k*8 + kc + 3)
            const int kc3 = (kc + 3) & 7;
            const float* iA = (kc < 5) ? xAc : xAn;
            const float* iB = (kc < 5) ? xBc : xBn;
            issue_chunk(XCH, bc, iA, iB, kc3, wave, lane);
            bc = (bc == 2) ? 0 : bc + 1;
        }

        // ---- h-write; C/D layout col=lane&15, row=(lane>>4)*4+j [m89] ----
        u16 (*H)[264] = sel ? HB : HA;
#pragma unroll
        for (int rt = 0; rt < 4; ++rt)
#pragma unroll
            for (int u = 0; u < 4; ++u) {
                const int cc = g * 64 + u * 16 + ar;
#pragma unroll
                for (int j = 0; j < 4; ++j)
                    H[rt * 16 + kg * 4 + j][cc] = f2bf(acc[rt][u][j]);
            }
        asm volatile("s_waitcnt lgkmcnt(0)" ::: "memory");   // ds_writes visible
        __builtin_amdgcn_s_barrier();                        // NO vmcnt drain
        __builtin_amdgcn_sched_barrier(0);

        // ---- score: wave = (head g, row-half sel) ----
        float sum = 0.f;
        {
            const int hc = g * 64;
            bf16x8 aS[2][2];
#pragma unroll
            for (int rt = 0; rt < 2; ++rt)
#pragma unroll
                for (int kk = 0; kk < 2; ++kk)
                    aS[rt][kk] = *(const bf16x8*)
                        &HA[sel * 32 + rt * 16 + ar][hc + kk * 32 + k0];
#pragma unroll
            for (int bu = 0; bu < 4; ++bu) {
                bf16x8 b0 = *(const bf16x8*)&HB[bu * 16 + ar][hc + k0];
                bf16x8 b1 = *(const bf16x8*)&HB[bu * 16 + ar][hc + 32 + k0];
#pragma unroll
                for (int rt = 0; rt < 2; ++rt) {
                    f32x4 c = {};
                    c = mfma16(aS[rt][0], b0, c);
                    c = mfma16(aS[rt][1], b1, c);   // full k=64 BEFORE relu
                    sum += fmaxf(c[0], 0.f) + fmaxf(c[1], 0.f) +
                           fmaxf(c[2], 0.f) + fmaxf(c[3], 0.f);
                }
            }
        }
#pragma unroll
        for (int off = 32; off; off >>= 1) sum += __shfl_xor(sum, off);
        if (lane == 0) red[wave] = sum;
        asm volatile("s_waitcnt lgkmcnt(0)" ::: "memory");
        __builtin_amdgcn_s_barrier();
        if (tid == 0) {
            const float nP = nItem[p], nQ = nItem[q];
            float v = 0.f;
#pragma unroll
            for (int h = 0; h < 4; ++h)
                v += ((((red[h] + red[h + 4]) * 0.125f) / nQ) / nP) * W2[h];
            out[p * NSET + q] = v;
            out[q * NSET + p] = v;
        }

        // ---- advance pair (chunk stream already 3 deep into pair k+1) ----
        idx = nidx; p = pn; q = qn; xAc = xAn; xBc = xBn;
        nidx = idx + NBLK;
        if (nidx < NPAIR) {
            decode_pair(nidx, pn, qn);
            xAn = x + (size_t)(pn * NSET + qn) * (MITEM * FFEAT);
            xBn = x + (size_t)(qn * NSET + pn) * (MITEM * FFEAT);
        }   // else: keep (re-issue current, L3-hot, counts stay uniform)
    }
    asm volatile("s_waitcnt vmcnt(0)" ::: "memory");   // drain ring before end
}

extern "C" void kernel_launch(void* const* d_in, const int* in_sizes, int n_in,
                              void* d_out, int out_size, void* d_ws, size_t ws_size,
                              hipStream_t stream) {
    const float* x     = (const float*)d_in[0];
    const float* nItem = (const float*)d_in[1];
    const float* W1    = (const float*)d_in[2];
    const float* W2    = (const float*)d_in[3];
    float* out = (float*)d_out;

    u16* w1t = (u16*)d_ws;                 // 128 KiB
    if (ws_size < 131072) return;

    hipLaunchKernelGGL(prep_w1t_kernel, dim3(256), dim3(256), 0, stream, W1, w1t);
    hipLaunchKernelGGL(fused_kernel, dim3(NBLK), dim3(512), 0, stream,
                       x, w1t, nItem, W2, out);
}

// Round 10
// 141.947 us; speedup vs baseline: 1.1114x; 1.0377x over previous
//
#include <hip/hip_runtime.h>
#include <hip/hip_bf16.h>

// cross_set_score, fused, persistent, pair-level async-split (T14).
// x[64,64,64,256] f32. out[p,q]=out[q,p]= sum_h W2[h]*0.125*relu-sum(hA·hB^T)
//   / (nItem[p]*nItem[q]); hA=x[p,q]@W1, hB=x[q,p]@W1 (bf16 MFMA in-block).
// 512 persistent blocks (2/CU) x 256 thr (4 waves) — r3's proven geometry.
// Per pair: proj (r3) -> h in-place -> score frags hoisted to regs -> barrier
// frees LDS -> NEXT pair's x issue/cvt/ds_write interleaved with score MFMA
// clusters. Staging regs never live across a compute phase (r4-r9 lesson).

#define NSET 64
#define MITEM 64
#define FFEAT 256
#define NPAIR 2080
#define NBLK 512

typedef float f32x4 __attribute__((ext_vector_type(4)));
typedef short bf16x8 __attribute__((ext_vector_type(8)));
typedef unsigned short u16;
typedef u16 u16x4 __attribute__((ext_vector_type(4)));

__device__ __forceinline__ u16 f2bf(float f) {
    __bf16 b = (__bf16)f;
    return __builtin_bit_cast(u16, b);
}
__device__ __forceinline__ f32x4 mfma16(bf16x8 a, bf16x8 b, f32x4 c) {
    return __builtin_amdgcn_mfma_f32_16x16x32_bf16(a, b, c, 0, 0, 0);
}
__device__ __forceinline__ void decode_pair(int idx, int& p, int& q) {
    p = 0;
    while (idx >= NSET - p) { idx -= NSET - p; ++p; }
    q = p + idx;
}

// ---- prep: W1 [k=256][c=256] f32 -> W1T bf16 [c][k] (B-frags contiguous in k)
__global__ void prep_w1t_kernel(const float* __restrict__ w1, u16* __restrict__ w1t) {
    int c = blockIdx.x, k = threadIdx.x;
    w1t[c * 256 + k] = f2bf(w1[k * 256 + c]);
}

__global__ __launch_bounds__(256, 2) void fused_kernel(const float* __restrict__ x,
                                                       const u16* __restrict__ w1t,
                                                       const float* __restrict__ nItem,
                                                       const float* __restrict__ W2,
                                                       float* __restrict__ out) {
    // x-slice (bf16) during proj, then h, 528 B row stride (benign 2-way alias)
    __shared__ u16 BUFA[MITEM][264];   // 33.8 KiB
    __shared__ u16 BUFB[MITEM][264];   // 33.8 KiB
    __shared__ float red[4];

    const int tid  = threadIdx.x;
    const int lane = tid & 63;
    const int wave = tid >> 6;          // 0..3: proj col-group g == score head
    const int ar   = lane & 15;
    const int kg   = lane >> 4;
    const int k0   = kg * 8;
    const int g    = wave;

// one slice = 16384 f32; 256 thr x float4 -> 16 instrs, 4 KiB contiguous each
#define ISSUE(r, xs)                                                    \
    _Pragma("unroll")                                                   \
    for (int u = 0; u < 16; ++u) r[u] = *(const float4*)((xs) + u * 1024 + tid * 4);
#define CVT_WRITE(r, BUF)                                               \
    _Pragma("unroll")                                                   \
    for (int u = 0; u < 16; ++u) {                                      \
        const int f = u * 1024 + tid * 4;                               \
        const int rr = f >> 8, cc = f & 255;                            \
        u16x4 pk = { f2bf(r[u].x), f2bf(r[u].y), f2bf(r[u].z), f2bf(r[u].w) }; \
        *(u16x4*)&BUF[rr][cc] = pk;                                     \
    }

    int idx = blockIdx.x;
    int p, q; decode_pair(idx, p, q);

    // ---- prologue: stage pair idx (phase-local regs) -------------------------
    {
        const float* xA = x + (size_t)(p * NSET + q) * (MITEM * FFEAT);
        const float* xB = x + (size_t)(q * NSET + p) * (MITEM * FFEAT);
        float4 r[16];
        ISSUE(r, xA); CVT_WRITE(r, BUFA);
        ISSUE(r, xB); CVT_WRITE(r, BUFB);
    }

    for (;;) {
        __syncthreads();   // staged x visible (and red[] read done)

        // ---- proj: wave owns 64-col group g of BOTH slices (r3 verbatim) ----
        f32x4 accA[4][4] = {}, accB[4][4] = {};
#pragma unroll
        for (int kc = 0; kc < 8; ++kc) {
            bf16x8 bu[4], aA[4], aB[4];
#pragma unroll
            for (int u = 0; u < 4; ++u)
                bu[u] = *(const bf16x8*)(w1t + (size_t)(g * 64 + u * 16 + ar) * 256
                                             + kc * 32 + k0);
#pragma unroll
            for (int rt = 0; rt < 4; ++rt) {
                aA[rt] = *(const bf16x8*)&BUFA[rt * 16 + ar][kc * 32 + k0];
                aB[rt] = *(const bf16x8*)&BUFB[rt * 16 + ar][kc * 32 + k0];
            }
#pragma unroll
            for (int u = 0; u < 4; ++u)
#pragma unroll
                for (int rt = 0; rt < 4; ++rt) {
                    accA[rt][u] = mfma16(aA[rt], bu[u], accA[rt][u]);
                    accB[rt][u] = mfma16(aB[rt], bu[u], accB[rt][u]);
                }
        }
        __syncthreads();   // all x reads done before h overwrite

        // ---- h write in place; C/D: col=lane&15, row=(lane>>4)*4+j [m89] ----
#pragma unroll
        for (int rt = 0; rt < 4; ++rt)
#pragma unroll
            for (int u = 0; u < 4; ++u) {
                const int cc = g * 64 + u * 16 + ar;
#pragma unroll
                for (int j = 0; j < 4; ++j) {
                    BUFA[rt * 16 + kg * 4 + j][cc] = f2bf(accA[rt][u][j]);
                    BUFB[rt * 16 + kg * 4 + j][cc] = f2bf(accB[rt][u][j]);
                }
            }
        __syncthreads();   // h visible

        // ---- hoist ALL score operands to regs (head g): 16 frags = 64 VGPR --
        const int hc = g * 64;
        bf16x8 aS[4][2], bS[4][2];
#pragma unroll
        for (int rt = 0; rt < 4; ++rt)
#pragma unroll
            for (int kk = 0; kk < 2; ++kk) {
                aS[rt][kk] = *(const bf16x8*)&BUFA[rt * 16 + ar][hc + kk * 32 + k0];
                bS[rt][kk] = *(const bf16x8*)&BUFB[rt * 16 + ar][hc + kk * 32 + k0];
            }
        __syncthreads();   // h reads done -> LDS buffers free for next pair

        // ---- phase 4: next-pair staging interleaved with score MFMAs --------
        const int nidx = idx + NBLK;
        const bool last = nidx >= NPAIR;
        int np, nq; decode_pair(last ? idx : nidx, np, nq);
        const float* nxA = x + (size_t)(np * NSET + nq) * (MITEM * FFEAT);
        const float* nxB = x + (size_t)(nq * NSET + np) * (MITEM * FFEAT);

        float sum = 0.f;
        float4 r[16];

        ISSUE(r, nxA);                          // A loads fly under cluster 1
        __builtin_amdgcn_sched_barrier(0);
#pragma unroll
        for (int bu = 0; bu < 2; ++bu)
#pragma unroll
            for (int rt = 0; rt < 4; ++rt) {
                f32x4 c = {};
                c = mfma16(aS[rt][0], bS[bu][0], c);
                c = mfma16(aS[rt][1], bS[bu][1], c);   // full k=64 BEFORE relu
                sum += fmaxf(c[0], 0.f) + fmaxf(c[1], 0.f) +
                       fmaxf(c[2], 0.f) + fmaxf(c[3], 0.f);
            }
        __builtin_amdgcn_sched_barrier(0);
        CVT_WRITE(r, BUFA);                     // waits A data; HBM-bound stall

        ISSUE(r, nxB);                          // B loads fly under cluster 2
        __builtin_amdgcn_sched_barrier(0);
#pragma unroll
        for (int bu = 2; bu < 4; ++bu)
#pragma unroll
            for (int rt = 0; rt < 4; ++rt) {
                f32x4 c = {};
                c = mfma16(aS[rt][0], bS[bu][0], c);
                c = mfma16(aS[rt][1], bS[bu][1], c);
                sum += fmaxf(c[0], 0.f) + fmaxf(c[1], 0.f) +
                       fmaxf(c[2], 0.f) + fmaxf(c[3], 0.f);
            }
        __builtin_amdgcn_sched_barrier(0);
        CVT_WRITE(r, BUFB);

        // ---- reduce + output -------------------------------------------------
#pragma unroll
        for (int off = 32; off; off >>= 1) sum += __shfl_xor(sum, off);
        if (lane == 0) red[wave] = sum;
        __syncthreads();
        if (tid == 0) {
            const float nP = nItem[p], nQ = nItem[q];
            float v = 0.f;
#pragma unroll
            for (int h = 0; h < 4; ++h)
                v += (((red[h] * 0.125f) / nQ) / nP) * W2[h];
            out[p * NSET + q] = v;
            out[q * NSET + p] = v;
        }

        if (last) break;
        idx = nidx; p = np; q = nq;
    }
#undef ISSUE
#undef CVT_WRITE
}

extern "C" void kernel_launch(void* const* d_in, const int* in_sizes, int n_in,
                              void* d_out, int out_size, void* d_ws, size_t ws_size,
                              hipStream_t stream) {
    const float* x     = (const float*)d_in[0];
    const float* nItem = (const float*)d_in[1];
    const float* W1    = (const float*)d_in[2];
    const float* W2    = (const float*)d_in[3];
    float* out = (float*)d_out;

    u16* w1t = (u16*)d_ws;                 // 128 KiB
    if (ws_size < 131072) return;

    hipLaunchKernelGGL(prep_w1t_kernel, dim3(256), dim3(256), 0, stream, W1, w1t);
    hipLaunchKernelGGL(fused_kernel, dim3(NBLK), dim3(256), 0, stream,
                       x, w1t, nItem, W2, out);
}